// Round 1
// baseline (3425.322 us; speedup 1.0000x reference)
//
#include <hip/hip_runtime.h>
#include <math.h>

// SPINN forward, fp32 throughout (argmax trajectory sensitivity forbids bf16/f16).
// Per step: KA gates-GEMM -> Kmid LSTM cell/logits/argmax -> KB reduce-GEMM -> KC node+stack+gather.

#define B_ 128
#define CAP 42
#define XW 2048   // X row: [buf_h 0:512 | s1_h 512:1024 | s2_h 1024:1536 | th_old 1536:1792 | th_new 1792:2048]

__device__ __forceinline__ float sigm(float x) { return 1.f / (1.f + expf(-x)); }

// ---------------- repack weights ----------------
// W1T[k][n], k in [0,1792): k<1536 -> W_ih[n][k], else W_hh[n][k-1536].  N=1024
// W2T[k][n], k in [0,1280): k<512 -> W_right[n][k] (s1h), k<1024 -> W_left[n][k-512] (s2h), else W_track[n][k-1024]. N=2560
__global__ void k_repack(const float* __restrict__ W_ih, const float* __restrict__ W_hh,
                         const float* __restrict__ W_left, const float* __restrict__ W_right,
                         const float* __restrict__ W_track, const float* __restrict__ b_ih,
                         const float* __restrict__ b_hh,
                         float* __restrict__ W1T, float* __restrict__ W2T, float* __restrict__ b1) {
    size_t idx = (size_t)blockIdx.x * 256 + threadIdx.x;
    const size_t n1 = 1792ull * 1024ull;          // 1,835,008
    const size_t n2 = 1280ull * 2560ull;          // 3,276,800
    if (idx < n1) {
        int k = (int)(idx >> 10), n = (int)(idx & 1023);
        W1T[idx] = (k < 1536) ? W_ih[(size_t)n * 1536 + k] : W_hh[(size_t)n * 256 + (k - 1536)];
    } else if (idx < n1 + n2) {
        size_t r = idx - n1;
        int k = (int)(r / 2560), n = (int)(r % 2560);
        float v;
        if (k < 512)       v = W_right[(size_t)n * 512 + k];
        else if (k < 1024) v = W_left [(size_t)n * 512 + (k - 512)];
        else               v = W_track[(size_t)n * 256 + (k - 1024)];
        W2T[r] = v;
    } else if (idx < n1 + n2 + 1024) {
        int i = (int)(idx - n1 - n2);
        b1[i] = b_ih[i] + b_hh[i];
    }
}

// ---------------- init state ----------------
__global__ void k_init(const float* __restrict__ buffers, float* __restrict__ stack,
                       float* __restrict__ X, float* __restrict__ tc,
                       int* __restrict__ sptr, int* __restrict__ blen) {
    int b = blockIdx.x, t = threadIdx.x;
    const float* b0 = buffers + (size_t)b * 40 * 1024;      // buffers[b][0]
    const float* btop = b0 + 39 * 1024;                     // buffers[b][39]
    float* stk = stack + (size_t)b * CAP * 1024;
    for (int j = t; j < 1024; j += 256) { stk[j] = b0[j]; stk[1024 + j] = b0[j]; }
    float* Xb = X + (size_t)b * XW;
    for (int j = t; j < 512; j += 256) {
        Xb[j] = btop[j]; Xb[512 + j] = b0[j]; Xb[1024 + j] = b0[j];
    }
    Xb[1536 + t] = 0.f;           // th_old = 0
    Xb[1792 + t] = 0.f;
    tc[b * 256 + t] = 0.f;
    if (t == 0) { sptr[b] = 2; blen[b] = 40; }
}

// ---------------- tiled fp32 GEMM with k-split partials ----------------
// C_part[kc][row][n0+n] = sum_{k in chunk} X[row][acol(k)] * WT[k][n]
// kmode 0: acol=k (K=1792). kmode 1: acol = k<1024 ? k+512 : k+768 (K=1280).
#define KT 32
__global__ __launch_bounds__(256, 3) void k_gemm(const float* __restrict__ X,
                                                 const float* __restrict__ WT,
                                                 float* __restrict__ part,
                                                 int N, int KS, int kmode) {
    __shared__ float As[KT][132];
    __shared__ float Ws[KT][132];
    const int n0 = blockIdx.x * 128;
    const int k0 = blockIdx.y * KS;
    const int tid = threadIdx.x;
    const int tm = tid >> 4;      // 0..15
    const int tn = tid & 15;      // 0..15

    float acc[8][8];
#pragma unroll
    for (int i = 0; i < 8; i++)
#pragma unroll
        for (int j = 0; j < 8; j++) acc[i][j] = 0.f;

    for (int ki = 0; ki < KS; ki += KT) {
        const int kb = k0 + ki;
        const int aoff = (kmode == 0) ? 0 : (kb < 1024 ? 512 : 768);
        __syncthreads();
        {   // stage A: As[kk][m] = X[m][aoff+kb+kk] ; 2 threads per row, 16 floats each
            int m = tid >> 1;
            int c8 = (tid & 1) * 16;
            const float4* src = (const float4*)(X + (size_t)m * XW + aoff + kb + c8);
#pragma unroll
            for (int j = 0; j < 4; j++) {
                float4 v = src[j];
                int kk = c8 + j * 4;
                As[kk + 0][m] = v.x; As[kk + 1][m] = v.y; As[kk + 2][m] = v.z; As[kk + 3][m] = v.w;
            }
        }
        {   // stage W: Ws[kk][n] = WT[kb+kk][n0+n] ; 8 threads per k-row, 16 floats each
            int kk = tid >> 3;
            int c = (tid & 7) * 16;
            const float4* src = (const float4*)(WT + (size_t)(kb + kk) * N + n0 + c);
            float4* dst = (float4*)(&Ws[kk][c]);
#pragma unroll
            for (int j = 0; j < 4; j++) dst[j] = src[j];
        }
        __syncthreads();
#pragma unroll 4
        for (int kk = 0; kk < KT; kk++) {
            float a[8], w[8];
            *(float4*)&a[0] = *(const float4*)&As[kk][tm * 4];
            *(float4*)&a[4] = *(const float4*)&As[kk][64 + tm * 4];
            *(float4*)&w[0] = *(const float4*)&Ws[kk][tn * 4];
            *(float4*)&w[4] = *(const float4*)&Ws[kk][64 + tn * 4];
#pragma unroll
            for (int i = 0; i < 8; i++)
#pragma unroll
                for (int j = 0; j < 8; j++) acc[i][j] += a[i] * w[j];
        }
    }
    // store partials: part[blockIdx.y][row][n]
    float* base = part + (size_t)blockIdx.y * 128 * N + n0;
#pragma unroll
    for (int i = 0; i < 8; i++) {
        int m = (i < 4) ? (tm * 4 + i) : (64 + tm * 4 + (i - 4));
        float4 v0 = make_float4(acc[i][0], acc[i][1], acc[i][2], acc[i][3]);
        float4 v1 = make_float4(acc[i][4], acc[i][5], acc[i][6], acc[i][7]);
        *(float4*)(base + (size_t)m * N + tn * 4) = v0;
        *(float4*)(base + (size_t)m * N + 64 + tn * 4) = v1;
    }
}

// ---------------- LSTM cell + logits + argmax ----------------
#define KSPLIT1 28
__global__ __launch_bounds__(256) void k_mid(const float* __restrict__ gates_part,
                                             float* __restrict__ tc, float* __restrict__ X,
                                             const float* __restrict__ W_trans,
                                             const float* __restrict__ b_trans,
                                             const float* __restrict__ b1,
                                             int* __restrict__ trans, float* __restrict__ out_s) {
    int b = blockIdx.x, t = threadIdx.x;
    const float* gp = gates_part + (size_t)b * 1024;
    float gi = b1[t], gf = b1[256 + t], gg = b1[512 + t], go = b1[768 + t];
#pragma unroll 4
    for (int kc = 0; kc < KSPLIT1; kc++) {
        const float* p = gp + (size_t)kc * 128 * 1024;
        gi += p[t]; gf += p[256 + t]; gg += p[512 + t]; go += p[768 + t];
    }
    float tcv = tc[b * 256 + t];
    float tcn = sigm(gf) * tcv + sigm(gi) * tanhf(gg);
    float thn = sigm(go) * tanhf(tcn);
    tc[b * 256 + t] = tcn;
    X[(size_t)b * XW + 1792 + t] = thn;

    __shared__ float red[256][4];
    red[t][0] = thn * W_trans[t];
    red[t][1] = thn * W_trans[256 + t];
    red[t][2] = thn * W_trans[512 + t];
    red[t][3] = thn * W_trans[768 + t];
    __syncthreads();
    for (int off = 128; off > 0; off >>= 1) {
        if (t < off) {
            red[t][0] += red[t + off][0]; red[t][1] += red[t + off][1];
            red[t][2] += red[t + off][2]; red[t][3] += red[t + off][3];
        }
        __syncthreads();
    }
    if (t == 0) {
        float lg[4];
        int tr = 0; float best = -1e30f;
#pragma unroll
        for (int l = 0; l < 4; l++) {
            lg[l] = red[0][l] + b_trans[l];
            if (lg[l] > best) { best = lg[l]; tr = l; }   // first-max like jnp.argmax
            out_s[b * 4 + l] = lg[l];
        }
        trans[b] = tr;
    }
}

// ---------------- TreeLSTM node + stack update + gather next X ----------------
#define KSPLIT2 10
__global__ __launch_bounds__(256) void k_kc(const float* __restrict__ lstm5_part,
                                            const float* __restrict__ b_left,
                                            const int* __restrict__ trans,
                                            int* __restrict__ sptr, int* __restrict__ blen,
                                            float* __restrict__ stack,
                                            const float* __restrict__ buffers,
                                            float* __restrict__ X) {
    int b = blockIdx.x, t = threadIdx.x;
    int tr = trans[b], sp = sptr[b], bl = blen[b];
    bool do_shift = (tr == 3) && (bl > 2);
    bool do_red   = (tr == 2) && (sp > 3);
    float* stk = stack + (size_t)b * CAP * 1024;
    __shared__ float nodeh[512];
    __shared__ float nodec[512];

    if (do_red) {
        const float* lp = lstm5_part + (size_t)b * 2560;
        const float* s1 = stk + (size_t)(sp - 1) * 1024;
        const float* s2 = stk + (size_t)(sp - 2) * 1024;
        for (int j = t; j < 512; j += 256) {
            float a = b_left[j], i_ = b_left[512 + j], f1 = b_left[1024 + j],
                  f2 = b_left[1536 + j], o = b_left[2048 + j];
#pragma unroll
            for (int kc = 0; kc < KSPLIT2; kc++) {
                const float* p = lp + (size_t)kc * 128 * 2560;
                a += p[j]; i_ += p[512 + j]; f1 += p[1024 + j]; f2 += p[1536 + j]; o += p[2048 + j];
            }
            float c = tanhf(a) * sigm(i_) + sigm(f1) * s2[512 + j] + sigm(f2) * s1[512 + j];
            float h = sigm(o) * tanhf(c);
            nodeh[j] = h; nodec[j] = c;
        }
    }
    __syncthreads();   // all reads of s1/s2 done before overwriting stack[sp-2]
    if (do_red) {
        float* dst = stk + (size_t)(sp - 2) * 1024;
        for (int j = t; j < 512; j += 256) { dst[j] = nodeh[j]; dst[512 + j] = nodec[j]; }
    }
    if (do_shift) {
        const float* bt = buffers + ((size_t)b * 40 + (bl - 1)) * 1024;
        float* dst = stk + (size_t)sp * 1024;
        for (int j = t; j < 1024; j += 256) dst[j] = bt[j];
    }
    int spn = sp + (do_shift ? 1 : 0) - (do_red ? 1 : 0);
    int bln = bl - (do_shift ? 1 : 0);
    if (t == 0) { sptr[b] = spn; blen[b] = bln; }
    __syncthreads();

    // gather next X row (per-row contiguous, coalesced)
    float* Xb = X + (size_t)b * XW;
    const float* btn = buffers + ((size_t)b * 40 + (bln - 1)) * 1024;
    for (int j = t; j < 512; j += 256) Xb[j] = btn[j];
    // s1' = stack[spn-1]
    if (do_red) {
        for (int j = t; j < 512; j += 256) Xb[512 + j] = nodeh[j];   // just-written node: use LDS copy
    } else if (do_shift) {
        const float* src = buffers + ((size_t)b * 40 + (bl - 1)) * 1024;  // just-pushed buf_top
        for (int j = t; j < 512; j += 256) Xb[512 + j] = src[j];
    } else {
        const float* src = stk + (size_t)(sp - 1) * 1024;
        for (int j = t; j < 512; j += 256) Xb[512 + j] = src[j];
    }
    // s2' = stack[spn-2]  (untouched slot in all three cases: sp-3 / sp-1 / sp-2)
    {
        const float* src = stk + (size_t)(spn - 2) * 1024;
        for (int j = t; j < 512; j += 256) Xb[1024 + j] = src[j];
    }
    // th_old <- th_new
    Xb[1536 + t] = Xb[1792 + t];
}

// ---------------- host ----------------
extern "C" void kernel_launch(void* const* d_in, const int* in_sizes, int n_in,
                              void* d_out, int out_size, void* d_ws, size_t ws_size,
                              hipStream_t stream) {
    const float* buffers = (const float*)d_in[0];
    const float* W_left  = (const float*)d_in[1];
    const float* b_left  = (const float*)d_in[2];
    const float* W_right = (const float*)d_in[3];
    const float* W_track = (const float*)d_in[4];
    const float* W_ih    = (const float*)d_in[5];
    const float* W_hh    = (const float*)d_in[6];
    const float* b_ih    = (const float*)d_in[7];
    const float* b_hh    = (const float*)d_in[8];
    const float* W_trans = (const float*)d_in[9];
    const float* b_trans = (const float*)d_in[10];
    float* out = (float*)d_out;

    float* ws = (float*)d_ws;
    size_t off = 0;
    float* W1T        = ws + off; off += 1792ull * 1024;        // 1,835,008
    float* W2T        = ws + off; off += 1280ull * 2560;        // 3,276,800
    float* b1         = ws + off; off += 1024;
    float* X          = ws + off; off += (size_t)B_ * XW;       // 262,144
    float* tc         = ws + off; off += (size_t)B_ * 256;
    float* gates_part = ws + off; off += (size_t)KSPLIT1 * B_ * 1024;   // 3,670,016
    float* lstm5_part = ws + off; off += (size_t)KSPLIT2 * B_ * 2560;   // 3,276,800
    float* stack      = ws + off; off += (size_t)B_ * CAP * 1024;       // 5,505,024
    int*   trans      = (int*)(ws + off); off += 128;
    int*   sptr       = (int*)(ws + off); off += 128;
    int*   blen       = (int*)(ws + off); off += 128;

    // one-time (per launch) weight repack + state init
    {
        size_t total = 1792ull * 1024 + 1280ull * 2560 + 1024;
        int blocks = (int)((total + 255) / 256);
        k_repack<<<blocks, 256, 0, stream>>>(W_ih, W_hh, W_left, W_right, W_track, b_ih, b_hh,
                                             W1T, W2T, b1);
        k_init<<<B_, 256, 0, stream>>>(buffers, stack, X, tc, sptr, blen);
    }

    for (int s = 0; s < 64; s++) {
        // gates = X[:, :1792] @ W1T + (b1 added in k_mid)
        k_gemm<<<dim3(8, KSPLIT1), 256, 0, stream>>>(X, W1T, gates_part, 1024, 64, 0);
        k_mid<<<B_, 256, 0, stream>>>(gates_part, tc, X, W_trans, b_trans, b1, trans,
                                      out + (size_t)s * B_ * 4);
        // lstm5 = [s1h|s2h|th_new] @ W2T  (b_left added in k_kc)
        k_gemm<<<dim3(20, KSPLIT2), 256, 0, stream>>>(X, W2T, lstm5_part, 2560, 128, 1);
        k_kc<<<B_, 256, 0, stream>>>(lstm5_part, b_left, trans, sptr, blen, stack, buffers, X);
    }
    (void)in_sizes; (void)n_in; (void)out_size; (void)ws_size;
}